// Round 11
// baseline (137.509 us; speedup 1.0000x reference)
//
#include <hip/hip_runtime.h>
#include <math.h>

#define BB 16
#define TT 2048
#define CC 32
#define HH 4
#define DD 8

#define KBS 2056      // per-wave K buffer stride in halves (256*8 + 8 pad)
#define VRS 264       // V^T row stride in halves (256 + 8 pad)
#define VBS (9 * VRS) // per-wave V buffer halves
#define ZP 33         // LDS row stride in floats

typedef __fp16 h2  __attribute__((ext_vector_type(2)));
typedef __fp16 h8  __attribute__((ext_vector_type(8)));
typedef float  fx16 __attribute__((ext_vector_type(16)));
typedef int    i4v __attribute__((ext_vector_type(4)));

__device__ __forceinline__ h2 pkh(float a, float b) {
#if __has_builtin(__builtin_amdgcn_cvt_pkrtz)
    return __builtin_amdgcn_cvt_pkrtz(a, b);
#else
    h2 r; r.x = (__fp16)a; r.y = (__fp16)b; return r;
#endif
}

__device__ __forceinline__ float fexp2(float x) {
#if __has_builtin(__builtin_amdgcn_exp2f)
    return __builtin_amdgcn_exp2f(x);
#else
    return exp2f(x);
#endif
}

__device__ __forceinline__ int h2bits(h2 v) { return __builtin_bit_cast(int, v); }

// S (QK^T C-layout) -> exp -> two B-operand P fragments (verified R7-R10)
__device__ __forceinline__ void makeP(const fx16& S, bool last, int thr, int hi, h8* P) {
    float pe[16];
    #pragma unroll
    for (int r = 0; r < 16; r++) {
        const int ko = (r & 3) + 8 * (r >> 2);
        float sv = S[r];
        if (last) sv = (ko <= thr) ? sv : -INFINITY;
        pe[r] = fexp2(sv);
    }
    int Hh[8];
    #pragma unroll
    for (int i = 0; i < 8; i++) Hh[i] = h2bits(pkh(pe[2*i], pe[2*i+1]));
    #pragma unroll
    for (int s = 0; s < 2; s++) {
        const int b0 = 4 * s;
        int own0 = hi ? Hh[b0+2] : Hh[b0+0];
        int own1 = hi ? Hh[b0+3] : Hh[b0+1];
        int snd0 = hi ? Hh[b0+0] : Hh[b0+2];
        int snd1 = hi ? Hh[b0+1] : Hh[b0+3];
        int rcv0 = __shfl_xor(snd0, 32);
        int rcv1 = __shfl_xor(snd1, 32);
        i4v f;
        f.x = hi ? rcv0 : own0;
        f.y = hi ? rcv1 : own1;
        f.z = hi ? own0 : rcv0;
        f.w = hi ? own1 : rcv1;
        P[s] = __builtin_bit_cast(h8, f);
    }
}

// ---------------- Kernel 1: QKV projection (R9 version: y=3, looped heads) ----
__global__ __launch_bounds__(256) void qkv_kernel(
    const float* __restrict__ x,
    const float* __restrict__ Wq, const float* __restrict__ bq,
    const float* __restrict__ Wk, const float* __restrict__ bk,
    const float* __restrict__ Wv, const float* __restrict__ bv,
    __fp16* __restrict__ Qo, __fp16* __restrict__ Ko, __fp16* __restrict__ Vo)
{
    __shared__ float Xs[256 * ZP];
    const int tid = threadIdx.x;
    const int m = blockIdx.y;
    const int row0 = blockIdx.x * 256;

    {   // coalesced stage of 256 x-rows (32 KB), padded stride 33
        const float4* xg = (const float4*)(x + (size_t)row0 * CC);
        #pragma unroll
        for (int i = 0; i < 8; i++) {
            const int idx = tid + 256 * i;
            float4 f = xg[idx];
            const int w = idx * 4;
            float* d = &Xs[(w >> 5) * ZP + (w & 31)];
            d[0] = f.x; d[1] = f.y; d[2] = f.z; d[3] = f.w;
        }
    }
    __syncthreads();

    const int row = row0 + tid;
    const int b = row >> 11, t = row & 2047;

    float xr[CC];
    #pragma unroll
    for (int c = 0; c < CC; c++) xr[c] = Xs[tid * ZP + c];

    const float* W    = (m == 0) ? Wq : (m == 1) ? Wk : Wv;
    const float* bias = (m == 0) ? bq : (m == 1) ? bk : bv;

    for (int h = 0; h < HH; h++) {
        const int bh = b * HH + h;
        float o[DD];
        #pragma unroll
        for (int d = 0; d < DD; d++) {
            const int dd = h * DD + d;
            float acc = bias[dd];
            #pragma unroll
            for (int c = 0; c < CC; c++) acc += xr[c] * W[dd * CC + c];
            o[d] = acc;
        }
        if (m == 0) {
            const float qs = 0.3535533905932738f * 1.4426950408889634f;
            i4v qw;
            qw.x = h2bits(pkh(o[0]*qs, o[1]*qs)); qw.y = h2bits(pkh(o[2]*qs, o[3]*qs));
            qw.z = h2bits(pkh(o[4]*qs, o[5]*qs)); qw.w = h2bits(pkh(o[6]*qs, o[7]*qs));
            *(i4v*)(Qo + ((size_t)bh * TT + t) * DD) = qw;
        } else if (m == 1) {
            i4v kw;
            kw.x = h2bits(pkh(o[0], o[1])); kw.y = h2bits(pkh(o[2], o[3]));
            kw.z = h2bits(pkh(o[4], o[5])); kw.w = h2bits(pkh(o[6], o[7]));
            *(i4v*)(Ko + ((size_t)bh * TT + t) * DD) = kw;
        } else {
            __fp16* vt = Vo + (size_t)bh * 9 * TT + t;
            #pragma unroll
            for (int d = 0; d < DD; d++) vt[d * TT] = (__fp16)o[d];
            vt[8 * TT] = (__fp16)1.0f;
        }
    }
}

// ---------------- Kernel 2: fused attention + projection, 8-wave split-K -----
// Block 512 thr = 8 waves = (head, half). Wave A (half=0): qgroup ip fully
// (T1=ip+1 tiles, causal mask) + first sA=(63-2ip)/2 tiles of qgroup 63-ip
// => exactly 32 tiles. Wave B (half=1): remaining 33 tiles of qgroup 63-ip
// (incl. its mask tile). Partial O2 merged via LDS (no-max softmax => plain
// add, l rides along at O[4]). 2 blocks/CU -> 4 waves/SIMD, all waves busy,
// zero K-loop barriers (wave-private staging + register prefetch).
__global__ __launch_bounds__(512, 4) void attn_kernel(
    const __fp16* __restrict__ Qg, const __fp16* __restrict__ Kg,
    const __fp16* __restrict__ Vg,
    const float* __restrict__ Wp, const float* __restrict__ bp,
    float* __restrict__ out)
{
    __shared__ __align__(16) __fp16 KsS[8 * KBS];
    __shared__ __align__(16) __fp16 VtS[8 * VBS];
    __shared__ float zbuf[64 * ZP];

    const int tid   = threadIdx.x;
    const int b     = blockIdx.x & 15;
    const int ip    = blockIdx.x >> 4;      // pair index 0..31
    const int wavei = tid >> 6;
    const int h     = wavei >> 1;
    const int half  = wavei & 1;
    const int lane  = tid & 63;
    const int qc    = lane & 31;
    const int hi    = lane >> 5;

    const int bh  = b * HH + h;
    const int T1  = ip + 1;                 // qg1 tiles
    const int sA  = (63 - 2 * ip) >> 1;     // qg2 tiles taken by wave A
    const int qb1 = 32 * ip;
    const int qb2 = 32 * (63 - ip);

    const int ktLo = half ? 32 * sA : 0;
    const int ktHi = half ? 32 * (64 - ip) : 32 * max(T1, sA);
    const int g2lo = 32 * sA;               // g2 active (wave A): kt < g2lo

    h8 qf1, qf2;
    {   // B operands: Q^T (pre-scaled); hi half zero (annihilates A garbage)
        h8 qz;
        #pragma unroll
        for (int i = 0; i < 8; i++) qz[i] = (__fp16)0.0f;
        h8 qa = *(const h8*)(Qg + ((size_t)bh * TT + qb1 + qc) * DD);
        h8 qb = *(const h8*)(Qg + ((size_t)bh * TT + qb2 + qc) * DD);
        qf1 = hi ? qz : qa;
        qf2 = hi ? qz : qb;
    }

    fx16 O1, O2, zc;
    #pragma unroll
    for (int i = 0; i < 16; i++) { O1[i] = 0.0f; O2[i] = 0.0f; zc[i] = 0.0f; }

    const int vrow = (qc < 9) ? qc : 8;     // rows>=9 -> ones row (l trick)
    const int thr  = qc - 4 * hi;

    const __fp16* kgl = Kg + (size_t)bh * TT * DD;
    const __fp16* vgl = Vg + (size_t)bh * 9 * TT;
    __fp16* kld = KsS + wavei * KBS;        // wave-private
    __fp16* vld = VtS + wavei * VBS;
    const __fp16* kb = kld + qc * DD;
    const __fp16* vb = vld + vrow * VRS + 8 * hi;

    const int stLo = ktLo & ~255;

    i4v kpre[4], vpre[5];
    {   // prefetch first super-tile
        const i4v* ks = (const i4v*)(kgl + (size_t)stLo * DD);
        #pragma unroll
        for (int r = 0; r < 4; r++) kpre[r] = ks[lane + 64 * r];
        #pragma unroll
        for (int r = 0; r < 5; r++) {
            int i = lane + 64 * r; if (i > 287) i = 287;
            vpre[r] = *(const i4v*)(vgl + (i >> 5) * TT + stLo + (i & 31) * 8);
        }
    }

    for (int st = stLo; st < ktHi; st += 256) {
        {   // commit prefetched tile to wave-private LDS
            i4v* kd = (i4v*)kld;
            #pragma unroll
            for (int r = 0; r < 4; r++) kd[lane + 64 * r] = kpre[r];
            #pragma unroll
            for (int r = 0; r < 5; r++) {
                const int i = lane + 64 * r;
                if (i < 288) *(i4v*)(vld + (i >> 5) * VRS + (i & 31) * 8) = vpre[r];
            }
        }
        if (st + 256 < ktHi) {   // issue next tile's global loads (overlap compute)
            const int st2 = st + 256;
            const i4v* ks = (const i4v*)(kgl + (size_t)st2 * DD);
            #pragma unroll
            for (int r = 0; r < 4; r++) kpre[r] = ks[lane + 64 * r];
            #pragma unroll
            for (int r = 0; r < 5; r++) {
                int i = lane + 64 * r; if (i > 287) i = 287;
                vpre[r] = *(const i4v*)(vgl + (i >> 5) * TT + st2 + (i & 31) * 8);
            }
        }

        const int k0 = max(st, ktLo);
        const int k1 = min(st + 256, ktHi);
        for (int kt = k0; kt < k1; kt += 32) {
            const bool a1 = (half == 0) && (kt <= qb1);   // wave-uniform
            const bool a2 = half ? true : (kt < g2lo);

            h8 kf = *(const h8*)(kb + (kt - st) * DD);

            h8 P1[2], P2[2];
            if (a1) {
                fx16 S = __builtin_amdgcn_mfma_f32_32x32x16_f16(kf, qf1, zc, 0, 0, 0);
                makeP(S, kt == qb1, thr, hi, P1);
            }
            if (a2) {
                fx16 S = __builtin_amdgcn_mfma_f32_32x32x16_f16(kf, qf2, zc, 0, 0, 0);
                makeP(S, kt == qb2, thr, hi, P2);
            }
            #pragma unroll
            for (int s = 0; s < 2; s++) {
                h8 vf = *(const h8*)(vb + (kt - st) + 16 * s);
                if (a1) O1 = __builtin_amdgcn_mfma_f32_32x32x16_f16(vf, P1[s], O1, 0, 0, 0);
                if (a2) O2 = __builtin_amdgcn_mfma_f32_32x32x16_f16(vf, P2[s], O2, 0, 0, 0);
            }
        }
    }

    // ---- merge wave A's partial O2 into wave B (l rides at O[4]) ----
    __syncthreads();
    float* mb = (float*)(KsS + (size_t)(2 * h) * KBS);   // wave A's K buffer, 16B aligned
    if (half == 0) {
        #pragma unroll
        for (int r = 0; r < 16; r++) mb[r * 64 + lane] = O2[r];
    }
    __syncthreads();

    if (half == 0) {
        const float i1 = 1.0f / O1[4];
        float* z1 = &zbuf[qc * ZP + h * DD + 4 * hi];
        z1[0] = O1[0]*i1; z1[1] = O1[1]*i1; z1[2] = O1[2]*i1; z1[3] = O1[3]*i1;
    } else {
        #pragma unroll
        for (int r = 0; r < 16; r++) O2[r] += mb[r * 64 + lane];
        const float i2 = 1.0f / O2[4];
        float* z2 = &zbuf[(32 + qc) * ZP + h * DD + 4 * hi];
        z2[0] = O2[0]*i2; z2[1] = O2[1]*i2; z2[2] = O2[2]*i2; z2[3] = O2[3]*i2;
    }
    __syncthreads();

    {   // in-block projection: 8 waves x 4 output cols (uniform Wp -> s_loads)
        const int seg = wavei;
        const int r = lane;                 // rows 0-31 -> qg ip, 32-63 -> qg 63-ip
        float zr[CC];
        #pragma unroll
        for (int c = 0; c < CC; c++) zr[c] = zbuf[r * ZP + c];
        float o4[4];
        #pragma unroll
        for (int d = 0; d < 4; d++) {
            const int dd = seg * 4 + d;
            float acc = bp[dd];
            #pragma unroll
            for (int c = 0; c < CC; c++) acc += zr[c] * Wp[dd * CC + c];
            o4[d] = acc;
        }
        const int qglob = (r < 32) ? (qb1 + r) : (qb2 + (r - 32));
        float* dst = out + ((size_t)b * TT + qglob) * CC + seg * 4;
        *(float4*)dst = make_float4(o4[0], o4[1], o4[2], o4[3]);
    }
}

extern "C" void kernel_launch(void* const* d_in, const int* in_sizes, int n_in,
                              void* d_out, int out_size, void* d_ws, size_t ws_size,
                              hipStream_t stream) {
    const float* x  = (const float*)d_in[0];
    const float* Wq = (const float*)d_in[1];
    const float* bq = (const float*)d_in[2];
    const float* Wk = (const float*)d_in[3];
    const float* bk = (const float*)d_in[4];
    const float* Wv = (const float*)d_in[5];
    const float* bv = (const float*)d_in[6];
    const float* Wp = (const float*)d_in[7];
    const float* bp = (const float*)d_in[8];
    float* out = (float*)d_out;

    const size_t NE = (size_t)BB * HH * TT * DD;   // 1M
    __fp16* Qh = (__fp16*)d_ws;                    // 2 MB (pre-scaled)
    __fp16* Kh = Qh + NE;                          // 2 MB
    __fp16* Vt = Kh + NE;                          // 2.25 MB  [bh][9][T]

    qkv_kernel<<<dim3(BB * TT / 256, 3), 256, 0, stream>>>(x, Wq, bq, Wk, bk, Wv, bv, Qh, Kh, Vt);
    attn_kernel<<<dim3(BB * 32), 512, 0, stream>>>(Qh, Kh, Vt, Wp, bp, out);
}

// Round 12
// 124.683 us; speedup vs baseline: 1.1029x; 1.1029x over previous
//
#include <hip/hip_runtime.h>
#include <math.h>

#define BB 16
#define TT 2048
#define CC 32
#define HH 4
#define DD 8
#define ZP 33         // LDS row stride in floats

typedef __fp16 h2  __attribute__((ext_vector_type(2)));
typedef __fp16 h8  __attribute__((ext_vector_type(8)));
typedef float  fx16 __attribute__((ext_vector_type(16)));
typedef int    i4v __attribute__((ext_vector_type(4)));

__device__ __forceinline__ h2 pkh(float a, float b) {
#if __has_builtin(__builtin_amdgcn_cvt_pkrtz)
    return __builtin_amdgcn_cvt_pkrtz(a, b);
#else
    h2 r; r.x = (__fp16)a; r.y = (__fp16)b; return r;
#endif
}

__device__ __forceinline__ float fexp2(float x) {
#if __has_builtin(__builtin_amdgcn_exp2f)
    return __builtin_amdgcn_exp2f(x);
#else
    return exp2f(x);
#endif
}

__device__ __forceinline__ int h2bits(h2 v) { return __builtin_bit_cast(int, v); }

// S (QK^T C-layout) -> exp -> two B-operand P fragments (verified R7-R11)
__device__ __forceinline__ void makeP(const fx16& S, bool last, int thr, int hi, h8* P) {
    float pe[16];
    #pragma unroll
    for (int r = 0; r < 16; r++) {
        const int ko = (r & 3) + 8 * (r >> 2);
        float sv = S[r];
        if (last) sv = (ko <= thr) ? sv : -INFINITY;
        pe[r] = fexp2(sv);
    }
    int Hh[8];
    #pragma unroll
    for (int i = 0; i < 8; i++) Hh[i] = h2bits(pkh(pe[2*i], pe[2*i+1]));
    #pragma unroll
    for (int s = 0; s < 2; s++) {
        const int b0 = 4 * s;
        int own0 = hi ? Hh[b0+2] : Hh[b0+0];
        int own1 = hi ? Hh[b0+3] : Hh[b0+1];
        int snd0 = hi ? Hh[b0+0] : Hh[b0+2];
        int snd1 = hi ? Hh[b0+1] : Hh[b0+2+1];
        int rcv0 = __shfl_xor(snd0, 32);
        int rcv1 = __shfl_xor(snd1, 32);
        i4v f;
        f.x = hi ? rcv0 : own0;
        f.y = hi ? rcv1 : own1;
        f.z = hi ? own0 : rcv0;
        f.w = hi ? own1 : rcv1;
        P[s] = __builtin_bit_cast(h8, f);
    }
}

// One 32-key tile: QK MFMA (K direct from global) -> makeP
__device__ __forceinline__ void tileQK(const __fp16* kb, int kt, const h8& qf,
                                       const fx16& zc, bool last, int thr, int hi, h8* P) {
    h8 kf = *(const h8*)(kb + (size_t)kt * DD);
    fx16 S = __builtin_amdgcn_mfma_f32_32x32x16_f16(kf, qf, zc, 0, 0, 0);
    makeP(S, last, thr, hi, P);
}

// PV MFMAs (V^T direct from global)
__device__ __forceinline__ void tilePV(const __fp16* vb, int kt, const h8* P, fx16& O) {
    #pragma unroll
    for (int s = 0; s < 2; s++) {
        h8 vf = *(const h8*)(vb + kt + 16 * s);
        O = __builtin_amdgcn_mfma_f32_32x32x16_f16(vf, P[s], O, 0, 0, 0);
    }
}

// ---------------- Kernel 1: QKV projection (y=3, looped heads, LDS x-stage) ---
__global__ __launch_bounds__(256) void qkv_kernel(
    const float* __restrict__ x,
    const float* __restrict__ Wq, const float* __restrict__ bq,
    const float* __restrict__ Wk, const float* __restrict__ bk,
    const float* __restrict__ Wv, const float* __restrict__ bv,
    __fp16* __restrict__ Qo, __fp16* __restrict__ Ko, __fp16* __restrict__ Vo)
{
    __shared__ float Xs[256 * ZP];
    const int tid = threadIdx.x;
    const int m = blockIdx.y;
    const int row0 = blockIdx.x * 256;

    {   // coalesced stage of 256 x-rows (32 KB), padded stride 33
        const float4* xg = (const float4*)(x + (size_t)row0 * CC);
        #pragma unroll
        for (int i = 0; i < 8; i++) {
            const int idx = tid + 256 * i;
            float4 f = xg[idx];
            const int w = idx * 4;
            float* d = &Xs[(w >> 5) * ZP + (w & 31)];
            d[0] = f.x; d[1] = f.y; d[2] = f.z; d[3] = f.w;
        }
    }
    __syncthreads();

    const int row = row0 + tid;
    const int b = row >> 11, t = row & 2047;

    float xr[CC];
    #pragma unroll
    for (int c = 0; c < CC; c++) xr[c] = Xs[tid * ZP + c];

    const float* W    = (m == 0) ? Wq : (m == 1) ? Wk : Wv;
    const float* bias = (m == 0) ? bq : (m == 1) ? bk : bv;

    for (int h = 0; h < HH; h++) {
        const int bh = b * HH + h;
        float o[DD];
        #pragma unroll
        for (int d = 0; d < DD; d++) {
            const int dd = h * DD + d;
            float acc = bias[dd];
            #pragma unroll
            for (int c = 0; c < CC; c++) acc += xr[c] * W[dd * CC + c];
            o[d] = acc;
        }
        if (m == 0) {
            const float qs = 0.3535533905932738f * 1.4426950408889634f;
            i4v qw;
            qw.x = h2bits(pkh(o[0]*qs, o[1]*qs)); qw.y = h2bits(pkh(o[2]*qs, o[3]*qs));
            qw.z = h2bits(pkh(o[4]*qs, o[5]*qs)); qw.w = h2bits(pkh(o[6]*qs, o[7]*qs));
            *(i4v*)(Qo + ((size_t)bh * TT + t) * DD) = qw;
        } else if (m == 1) {
            i4v kw;
            kw.x = h2bits(pkh(o[0], o[1])); kw.y = h2bits(pkh(o[2], o[3]));
            kw.z = h2bits(pkh(o[4], o[5])); kw.w = h2bits(pkh(o[6], o[7]));
            *(i4v*)(Ko + ((size_t)bh * TT + t) * DD) = kw;
        } else {
            __fp16* vt = Vo + (size_t)bh * 9 * TT + t;
            #pragma unroll
            for (int d = 0; d < DD; d++) vt[d * TT] = (__fp16)o[d];
            vt[8 * TT] = (__fp16)1.0f;
        }
    }
}

// ---------------- Kernel 2: fused attention + projection, split-K, no staging -
// Block 512 thr = 8 waves = (head, half); pair {ip, 63-ip}. Wave A (half=0):
// g1 fully (T1 tiles) + g2 first sA tiles = 32 chain-tiles; wave B: remaining
// 33 g2 tiles incl. mask. K/V read DIRECT FROM GLOBAL (L2-resident, 4.25 MB
// working set) -> no staging arrays -> no spills at the (512,4) 128-reg cap.
// Partial O2 merged via LDS (no-max softmax => plain add; l rides at O[4]).
__global__ __launch_bounds__(512, 4) void attn_kernel(
    const __fp16* __restrict__ Qg, const __fp16* __restrict__ Kg,
    const __fp16* __restrict__ Vg,
    const float* __restrict__ Wp, const float* __restrict__ bp,
    float* __restrict__ out)
{
    __shared__ float mbuf[4 * 16 * 64];   // O2 partial merge (16 KB)
    __shared__ float zbuf[64 * ZP];

    const int tid   = threadIdx.x;
    const int b     = blockIdx.x & 15;
    const int ip    = blockIdx.x >> 4;      // pair index 0..31
    const int wavei = tid >> 6;
    const int h     = wavei >> 1;
    const int half  = wavei & 1;
    const int lane  = tid & 63;
    const int qc    = lane & 31;
    const int hi    = lane >> 5;

    const int bh  = b * HH + h;
    const int T1  = ip + 1;                 // g1 tiles
    const int sA  = 31 - ip;                // g2 tiles taken by wave A
    const int qb1 = 32 * ip;
    const int qb2 = 32 * (63 - ip);

    h8 qf1, qf2;
    {   // B operands: Q^T (pre-scaled); hi half zero (annihilates A garbage)
        h8 qz;
        #pragma unroll
        for (int i = 0; i < 8; i++) qz[i] = (__fp16)0.0f;
        h8 qa = *(const h8*)(Qg + ((size_t)bh * TT + qb1 + qc) * DD);
        h8 qb = *(const h8*)(Qg + ((size_t)bh * TT + qb2 + qc) * DD);
        qf1 = hi ? qz : qa;
        qf2 = hi ? qz : qb;
    }

    fx16 O1, O2, zc;
    #pragma unroll
    for (int i = 0; i < 16; i++) { O1[i] = 0.0f; O2[i] = 0.0f; zc[i] = 0.0f; }

    const int vrow = (qc < 9) ? qc : 8;     // rows>=9 -> ones row (l trick)
    const int thr  = qc - 4 * hi;

    const __fp16* kb = Kg + (size_t)bh * TT * DD + qc * DD;      // K row qc (+kt)
    const __fp16* vb = Vg + (size_t)bh * 9 * TT + vrow * TT + 8 * hi;

    if (half == 0) {
        const int mN = (T1 < sA) ? T1 : sA;
        const int xN = (T1 < sA) ? sA : T1;
        for (int t = 0; t < mN; t++) {      // dual-chain region (shared kf)
            const int kt = 32 * t;
            h8 P1[2], P2[2];
            tileQK(kb, kt, qf1, zc, kt == qb1, thr, hi, P1);
            tileQK(kb, kt, qf2, zc, false, thr, hi, P2);
            tilePV(vb, kt, P1, O1);
            tilePV(vb, kt, P2, O2);
        }
        if (T1 > sA) {                      // g1-only remainder, unroll x2 (even)
            for (int t = mN; t < xN; t += 2) {
                h8 Pa[2], Pb[2];
                tileQK(kb, 32 * t,       qf1, zc, 32 * t       == qb1, thr, hi, Pa);
                tileQK(kb, 32 * (t + 1), qf1, zc, 32 * (t + 1) == qb1, thr, hi, Pb);
                tilePV(vb, 32 * t,       Pa, O1);
                tilePV(vb, 32 * (t + 1), Pb, O1);
            }
        } else {                            // g2-only remainder, unroll x2 (even)
            for (int t = mN; t < xN; t += 2) {
                h8 Pa[2], Pb[2];
                tileQK(kb, 32 * t,       qf2, zc, false, thr, hi, Pa);
                tileQK(kb, 32 * (t + 1), qf2, zc, false, thr, hi, Pb);
                tilePV(vb, 32 * t,       Pa, O2);
                tilePV(vb, 32 * (t + 1), Pb, O2);
            }
        }
    } else {                                // wave B: 16 pairs + mask tile = 33
        for (int t = 0; t < 16; t++) {
            const int kt = 32 * sA + 64 * t;
            h8 Pa[2], Pb[2];
            tileQK(kb, kt,      qf2, zc, false, thr, hi, Pa);
            tileQK(kb, kt + 32, qf2, zc, false, thr, hi, Pb);
            tilePV(vb, kt,      Pa, O2);
            tilePV(vb, kt + 32, Pb, O2);
        }
        h8 Pm[2];
        tileQK(kb, qb2, qf2, zc, true, thr, hi, Pm);
        tilePV(vb, qb2, Pm, O2);
    }

    // ---- merge wave A's partial O2 into wave B (l rides at O[4]) ----
    __syncthreads();
    float* mb = &mbuf[h * 16 * 64];
    if (half == 0) {
        #pragma unroll
        for (int r = 0; r < 16; r++) mb[r * 64 + lane] = O2[r];
    }
    __syncthreads();

    if (half == 0) {
        const float i1 = 1.0f / O1[4];
        float* z1 = &zbuf[qc * ZP + h * DD + 4 * hi];
        z1[0] = O1[0]*i1; z1[1] = O1[1]*i1; z1[2] = O1[2]*i1; z1[3] = O1[3]*i1;
    } else {
        #pragma unroll
        for (int r = 0; r < 16; r++) O2[r] += mb[r * 64 + lane];
        const float i2 = 1.0f / O2[4];
        float* z2 = &zbuf[(32 + qc) * ZP + h * DD + 4 * hi];
        z2[0] = O2[0]*i2; z2[1] = O2[1]*i2; z2[2] = O2[2]*i2; z2[3] = O2[3]*i2;
    }
    __syncthreads();

    {   // in-block projection: 8 waves x 4 output cols (uniform Wp -> s_loads)
        const int seg = wavei;
        const int r = lane;                 // rows 0-31 -> qg ip, 32-63 -> qg 63-ip
        float zr[CC];
        #pragma unroll
        for (int c = 0; c < CC; c++) zr[c] = zbuf[r * ZP + c];
        float o4[4];
        #pragma unroll
        for (int d = 0; d < 4; d++) {
            const int dd = seg * 4 + d;
            float acc = bp[dd];
            #pragma unroll
            for (int c = 0; c < CC; c++) acc += zr[c] * Wp[dd * CC + c];
            o4[d] = acc;
        }
        const int qglob = (r < 32) ? (qb1 + r) : (qb2 + (r - 32));
        float* dst = out + ((size_t)b * TT + qglob) * CC + seg * 4;
        *(float4*)dst = make_float4(o4[0], o4[1], o4[2], o4[3]);
    }
}

extern "C" void kernel_launch(void* const* d_in, const int* in_sizes, int n_in,
                              void* d_out, int out_size, void* d_ws, size_t ws_size,
                              hipStream_t stream) {
    const float* x  = (const float*)d_in[0];
    const float* Wq = (const float*)d_in[1];
    const float* bq = (const float*)d_in[2];
    const float* Wk = (const float*)d_in[3];
    const float* bk = (const float*)d_in[4];
    const float* Wv = (const float*)d_in[5];
    const float* bv = (const float*)d_in[6];
    const float* Wp = (const float*)d_in[7];
    const float* bp = (const float*)d_in[8];
    float* out = (float*)d_out;

    const size_t NE = (size_t)BB * HH * TT * DD;   // 1M
    __fp16* Qh = (__fp16*)d_ws;                    // 2 MB (pre-scaled)
    __fp16* Kh = Qh + NE;                          // 2 MB
    __fp16* Vt = Kh + NE;                          // 2.25 MB  [bh][9][T]

    qkv_kernel<<<dim3(BB * TT / 256, 3), 256, 0, stream>>>(x, Wq, bq, Wk, bk, Wv, bv, Qh, Kh, Vt);
    attn_kernel<<<dim3(BB * 32), 512, 0, stream>>>(Qh, Kh, Vt, Wp, bp, out);
}